// Round 12
// baseline (26.196 us; speedup 1.0000x reference)
//
#include <hip/hip_runtime.h>
#include <math.h>

#define NACC 24
#define GRID1 1024
#define TPB 256
#define NTILE 4
// 1024 blocks x 256 threads x 4 tiles x 4 elems = 4194304 exactly

// canonical 24-vector layout:
//  0: lt count (dbp_pred < sbp_pred)
//  1: sum_d   2: sum_d2   3: sum_dp  4: sum_dp2
//  5: sum_s   6: sum_s2   7: sum_sp  8: sum_sp2
//  9+3g: mask-g count   10+3g: mask-g . smape_d   11+3g: mask-g . smape_s

// All-f32 per-thread accumulation (16 elems/thread): sums ~2e-7 rel error,
// counts <= 16 exact in f32; promoted to f64 before cross-thread summation.
__device__ __forceinline__ void process_elem(float* a, float dpv, float spv,
                                             float dv, float sv) {
    a[0] += (dpv < spv) ? 1.0f : 0.0f;
    a[1] += dv;  a[2] = fmaf(dv,  dv,  a[2]);
    a[3] += dpv; a[4] = fmaf(dpv, dpv, a[4]);
    a[5] += sv;  a[6] = fmaf(sv,  sv,  a[6]);
    a[7] += spv; a[8] = fmaf(spv, spv, a[8]);
    float smd = 2.0f * fabsf(dpv - dv) * __builtin_amdgcn_rcpf(fabsf(dpv) + fabsf(dv));
    float sms = 2.0f * fabsf(spv - sv) * __builtin_amdgcn_rcpf(fabsf(spv) + fabsf(sv));
    // mask precedence: & binds tighter than | in the reference
    bool m0 = (sv < 120.0f) && (dv < 80.0f);
    bool m1 = (sv >= 120.0f) && (sv < 130.0f) && (dv < 80.0f);
    bool m2 = ((sv >= 130.0f) && (sv < 140.0f)) || ((dv >= 80.0f) && (dv < 90.0f));
    bool m3 = (sv >= 140.0f) || (dv >= 90.0f);
    bool m4 = (sv > 180.0f) || (dv > 120.0f);
    float w;
    w = m0 ? 1.0f : 0.0f; a[9]  += w; a[10] = fmaf(w, smd, a[10]); a[11] = fmaf(w, sms, a[11]);
    w = m1 ? 1.0f : 0.0f; a[12] += w; a[13] = fmaf(w, smd, a[13]); a[14] = fmaf(w, sms, a[14]);
    w = m2 ? 1.0f : 0.0f; a[15] += w; a[16] = fmaf(w, smd, a[16]); a[17] = fmaf(w, sms, a[17]);
    w = m3 ? 1.0f : 0.0f; a[18] += w; a[19] = fmaf(w, smd, a[19]); a[20] = fmaf(w, sms, a[20]);
    w = m4 ? 1.0f : 0.0f; a[21] += w; a[22] = fmaf(w, smd, a[22]); a[23] = fmaf(w, sms, a[23]);
}

__device__ __forceinline__ void process4(float* a, float4 vdp, float4 vsp,
                                         float4 vd, float4 vs) {
    process_elem(a, vdp.x, vsp.x, vd.x, vs.x);
    process_elem(a, vdp.y, vsp.y, vd.y, vs.y);
    process_elem(a, vdp.z, vsp.z, vd.z, vs.z);
    process_elem(a, vdp.w, vsp.w, vd.w, vs.w);
}

// Software-pipelined grind, prefetch distance 2: triple-buffered register
// staging (named A/B/C, fully static), sched_barrier(0) between each issue
// group and the following compute. Prologue puts 12 loads (3 tiles) in
// flight; every compute phase runs with >= 2 tiles (8 loads) outstanding,
// covering ~1400 cycles of latency per exposure (vs ~700 at distance 1).
template <bool EXACT>
__global__ __launch_bounds__(TPB, 4) void amp_reduce(
    const float* __restrict__ dp, const float* __restrict__ sp,
    const float* __restrict__ d,  const float* __restrict__ s,
    double* __restrict__ partial, int n)
{
    __shared__ float  red[NACC][TPB];   // 24 KB
    __shared__ double red2[NACC][8];    // 1.5 KB

    const int tid  = threadIdx.x;
    const int n4   = n >> 2;
    const int gtid = blockIdx.x * TPB + tid;
    const int S    = GRID1 * TPB;       // float4 stride between tiles

    const float4* dp4 = (const float4*)dp;
    const float4* sp4 = (const float4*)sp;
    const float4* d4  = (const float4*)d;
    const float4* s4  = (const float4*)s;

    float a[NACC];
    #pragma unroll
    for (int k = 0; k < NACC; ++k) a[k] = 0.0f;

    if (EXACT) {
        const int i0 = gtid, i1 = gtid + S, i2 = gtid + 2 * S, i3 = gtid + 3 * S;
        // prologue: tiles 0,1,2 in flight (12 loads)
        float4 A0 = dp4[i0], A1 = sp4[i0], A2 = d4[i0], A3 = s4[i0];
        float4 B0 = dp4[i1], B1 = sp4[i1], B2 = d4[i1], B3 = s4[i1];
        float4 C0 = dp4[i2], C1 = sp4[i2], C2 = d4[i2], C3 = s4[i2];
        __builtin_amdgcn_sched_barrier(0);
        process4(a, A0, A1, A2, A3);            // tile 0 (t1,t2 in flight)
        A0 = dp4[i3]; A1 = sp4[i3]; A2 = d4[i3]; A3 = s4[i3];   // tile 3
        __builtin_amdgcn_sched_barrier(0);
        process4(a, B0, B1, B2, B3);            // tile 1 (t2,t3 in flight)
        __builtin_amdgcn_sched_barrier(0);
        process4(a, C0, C1, C2, C3);            // tile 2 (t3 in flight)
        process4(a, A0, A1, A2, A3);            // tile 3
    } else {
        const float4 z4 = make_float4(0.f, 0.f, 0.f, 0.f);
        #pragma unroll
        for (int t = 0; t < NTILE; ++t) {
            const int i = gtid + t * S;
            const bool p = i < n4;
            float4 v0 = p ? dp4[i] : z4;
            float4 v1 = p ? sp4[i] : z4;
            float4 v2 = p ? d4[i]  : z4;
            float4 v3 = p ? s4[i]  : z4;
            process4(a, v0, v1, v2, v3);
        }
    }

    // block reduction via LDS store-then-gather (no shuffles, no atomics)
    #pragma unroll
    for (int k = 0; k < NACC; ++k) red[k][tid] = a[k];     // conflict-free
    __syncthreads();

    if (tid < 192) {
        const int k = tid >> 3;        // 0..23
        const int j = tid & 7;         // 0..7 : owns threads j*32..j*32+31
        const float* row = &red[k][j * 32];
        double s0 = 0.0, s1 = 0.0, s2 = 0.0, s3 = 0.0;
        #pragma unroll
        for (int i = 0; i < 32; i += 4) {
            s0 += (double)row[(i + 0 + tid) & 31];
            s1 += (double)row[(i + 1 + tid) & 31];
            s2 += (double)row[(i + 2 + tid) & 31];
            s3 += (double)row[(i + 3 + tid) & 31];
        }
        red2[k][j] = (s0 + s1) + (s2 + s3);
    }
    __syncthreads();

    if (tid < NACC) {
        double v = 0.0;
        #pragma unroll
        for (int j = 0; j < 8; ++j) v += red2[tid][j];
        // transposed layout: column k contiguous over blocks -> coalesced stage-2
        partial[tid * GRID1 + blockIdx.x] = v;
    }
}

// 1024 threads = 16 waves; wave w reduces cols {w, w+16}. 4 independent
// accumulators so the load batches per column pipeline.
__global__ __launch_bounds__(1024) void amp_final(
    const double* __restrict__ partial, float* __restrict__ out, int n)
{
    __shared__ double tot[NACC];
    const int lane = threadIdx.x & 63;
    const int wave = threadIdx.x >> 6;

    for (int k = wave; k < NACC; k += 16) {
        const double* col = partial + k * GRID1 + lane;
        double v0 = 0.0, v1 = 0.0, v2 = 0.0, v3 = 0.0;
        #pragma unroll
        for (int r = 0; r < GRID1 / 64; r += 4) {
            v0 += col[(r + 0) * 64];
            v1 += col[(r + 1) * 64];
            v2 += col[(r + 2) * 64];
            v3 += col[(r + 3) * 64];
        }
        double v = (v0 + v1) + (v2 + v3);
        #pragma unroll
        for (int off = 32; off > 0; off >>= 1)
            v += __shfl_down(v, off, 64);
        if (lane == 0) tot[k] = v;
    }
    __syncthreads();

    if (threadIdx.x == 0) {
        const double nf = (double)n;
        const double lt = tot[0];
        const double sum_d  = tot[1], sum_d2  = tot[2];
        const double sum_dp = tot[3], sum_dp2 = tot[4];
        const double sum_s  = tot[5], sum_s2  = tot[6];
        const double sum_sp = tot[7], sum_sp2 = tot[8];

        double scale_cost = 1.0 - lt / nf;

        double d_rst = 0.0, s_rst = 0.0, rst_d = 0.0, rst_s = 0.0;
        int cnt = 0;
        #pragma unroll
        for (int i = 0; i < 5; ++i) {
            double c   = tot[9 + 3 * i];
            double sdi = tot[10 + 3 * i];
            double ssi = tot[11 + 3 * i];
            double safe = fmax(c, 1.0);
            double w = sqrt(log(nf / safe));
            double sum_di = w * sdi;
            double sum_si = w * ssi;
            bool has = c > 0.0;
            double nd = (d_rst + sum_di) / safe;
            double ns = (s_rst + sum_si) / safe;
            if (has) {
                d_rst = nd; s_rst = ns;
                rst_d += nd; rst_s += ns;
                cnt++;
            }
        }
        double denom = (cnt == 0) ? 5.0 : (double)cnt;
        rst_d /= denom;
        rst_s /= denom;

        double mean_d  = sum_d / nf,  mean_dp = sum_dp / nf;
        double mean_s  = sum_s / nf,  mean_sp = sum_sp / nf;
        double var_d  = (sum_d2  - nf * mean_d  * mean_d)  / (nf - 1.0);
        double var_dp = (sum_dp2 - nf * mean_dp * mean_dp) / (nf - 1.0);
        double var_s  = (sum_s2  - nf * mean_s  * mean_s)  / (nf - 1.0);
        double var_sp = (sum_sp2 - nf * mean_sp * mean_sp) / (nf - 1.0);

        double dbp_mean_cost = fabs(mean_d - mean_dp) / mean_d;
        double sbp_mean_cost = fabs(mean_s - mean_sp) / mean_s;
        double dbp_var_cost  = fabs(var_d - var_dp) / var_d;
        double sbp_var_cost  = fabs(var_s - var_sp) / var_s;

        out[0] = (float)(rst_d + dbp_mean_cost + dbp_var_cost);
        out[1] = (float)(rst_s + sbp_mean_cost + sbp_var_cost);
        out[2] = (float)scale_cost;
    }
}

extern "C" void kernel_launch(void* const* d_in, const int* in_sizes, int n_in,
                              void* d_out, int out_size, void* d_ws, size_t ws_size,
                              hipStream_t stream) {
    const float* dp = (const float*)d_in[0];   // dbp_pred
    const float* sp = (const float*)d_in[1];   // sbp_pred
    // d_in[2] = mbp_pred (unused), d_in[5] = m (unused)
    const float* d  = (const float*)d_in[3];
    const float* s  = (const float*)d_in[4];
    const int n = in_sizes[0];

    double* partial = (double*)d_ws;           // NACC * GRID1 doubles = 192 KiB
    float* out = (float*)d_out;

    if (n == GRID1 * TPB * 4 * NTILE) {
        hipLaunchKernelGGL((amp_reduce<true>), dim3(GRID1), dim3(TPB), 0, stream,
                           dp, sp, d, s, partial, n);
    } else {
        hipLaunchKernelGGL((amp_reduce<false>), dim3(GRID1), dim3(TPB), 0, stream,
                           dp, sp, d, s, partial, n);
    }
    hipLaunchKernelGGL(amp_final, dim3(1), dim3(1024), 0, stream,
                       partial, out, n);
}

// Round 13
// 24.981 us; speedup vs baseline: 1.0486x; 1.0486x over previous
//
#include <hip/hip_runtime.h>
#include <math.h>

#define NACC 24
#define GRID1 1024
#define TPB 256
#define NTILE 4
// 1024 blocks x 256 threads x 4 tiles x 4 elems = 4194304 exactly

// canonical 24-vector layout:
//  0: lt count (dbp_pred < sbp_pred)
//  1: sum_d   2: sum_d2   3: sum_dp  4: sum_dp2
//  5: sum_s   6: sum_s2   7: sum_sp  8: sum_sp2
//  9+3g: mask-g count   10+3g: mask-g . smape_d   11+3g: mask-g . smape_s

// All-f32 per-thread accumulation (16 elems/thread): sums ~2e-7 rel error,
// counts <= 16 exact in f32; promoted to f64 for the in-block tree. Per-block
// partials are stored as f32 (rel ~1e-7 -> ~1e-6 absolute on outputs, vs
// 2.5e-3 threshold).
__device__ __forceinline__ void process_elem(float* a, float dpv, float spv,
                                             float dv, float sv) {
    a[0] += (dpv < spv) ? 1.0f : 0.0f;
    a[1] += dv;  a[2] = fmaf(dv,  dv,  a[2]);
    a[3] += dpv; a[4] = fmaf(dpv, dpv, a[4]);
    a[5] += sv;  a[6] = fmaf(sv,  sv,  a[6]);
    a[7] += spv; a[8] = fmaf(spv, spv, a[8]);
    float smd = 2.0f * fabsf(dpv - dv) * __builtin_amdgcn_rcpf(fabsf(dpv) + fabsf(dv));
    float sms = 2.0f * fabsf(spv - sv) * __builtin_amdgcn_rcpf(fabsf(spv) + fabsf(sv));
    // mask precedence: & binds tighter than | in the reference
    bool m0 = (sv < 120.0f) && (dv < 80.0f);
    bool m1 = (sv >= 120.0f) && (sv < 130.0f) && (dv < 80.0f);
    bool m2 = ((sv >= 130.0f) && (sv < 140.0f)) || ((dv >= 80.0f) && (dv < 90.0f));
    bool m3 = (sv >= 140.0f) || (dv >= 90.0f);
    bool m4 = (sv > 180.0f) || (dv > 120.0f);
    float w;
    w = m0 ? 1.0f : 0.0f; a[9]  += w; a[10] = fmaf(w, smd, a[10]); a[11] = fmaf(w, sms, a[11]);
    w = m1 ? 1.0f : 0.0f; a[12] += w; a[13] = fmaf(w, smd, a[13]); a[14] = fmaf(w, sms, a[14]);
    w = m2 ? 1.0f : 0.0f; a[15] += w; a[16] = fmaf(w, smd, a[16]); a[17] = fmaf(w, sms, a[17]);
    w = m3 ? 1.0f : 0.0f; a[18] += w; a[19] = fmaf(w, smd, a[19]); a[20] = fmaf(w, sms, a[20]);
    w = m4 ? 1.0f : 0.0f; a[21] += w; a[22] = fmaf(w, smd, a[22]); a[23] = fmaf(w, sms, a[23]);
}

__device__ __forceinline__ void process4(float* a, float4 vdp, float4 vsp,
                                         float4 vd, float4 vs) {
    process_elem(a, vdp.x, vsp.x, vd.x, vs.x);
    process_elem(a, vdp.y, vsp.y, vd.y, vs.y);
    process_elem(a, vdp.z, vsp.z, vd.z, vs.z);
    process_elem(a, vdp.w, vsp.w, vd.w, vs.w);
}

// Round-11 grind (distance-1 double-buffered register pipeline) unchanged;
// only the per-block partial store narrows to f32.
template <bool EXACT>
__global__ __launch_bounds__(TPB, 4) void amp_reduce(
    const float* __restrict__ dp, const float* __restrict__ sp,
    const float* __restrict__ d,  const float* __restrict__ s,
    float* __restrict__ partial, int n)
{
    __shared__ float  red[NACC][TPB];   // 24 KB
    __shared__ double red2[NACC][8];    // 1.5 KB

    const int tid  = threadIdx.x;
    const int n4   = n >> 2;
    const int gtid = blockIdx.x * TPB + tid;
    const int S    = GRID1 * TPB;       // float4 stride between tiles

    const float4* dp4 = (const float4*)dp;
    const float4* sp4 = (const float4*)sp;
    const float4* d4  = (const float4*)d;
    const float4* s4  = (const float4*)s;

    float a[NACC];
    #pragma unroll
    for (int k = 0; k < NACC; ++k) a[k] = 0.0f;

    if (EXACT) {
        int i = gtid;
        // prologue: tiles 0 and 1 in flight
        float4 A0 = dp4[i], A1 = sp4[i], A2 = d4[i], A3 = s4[i];
        i += S;
        float4 B0 = dp4[i], B1 = sp4[i], B2 = d4[i], B3 = s4[i];
        __builtin_amdgcn_sched_barrier(0);
        process4(a, A0, A1, A2, A3);            // tile 0 (covers tile 1)
        i += S;
        A0 = dp4[i]; A1 = sp4[i]; A2 = d4[i]; A3 = s4[i];   // tile 2
        __builtin_amdgcn_sched_barrier(0);
        process4(a, B0, B1, B2, B3);            // tile 1 (covers tile 2)
        i += S;
        B0 = dp4[i]; B1 = sp4[i]; B2 = d4[i]; B3 = s4[i];   // tile 3
        __builtin_amdgcn_sched_barrier(0);
        process4(a, A0, A1, A2, A3);            // tile 2 (covers tile 3)
        process4(a, B0, B1, B2, B3);            // tile 3
    } else {
        const float4 z4 = make_float4(0.f, 0.f, 0.f, 0.f);
        #pragma unroll
        for (int t = 0; t < NTILE; ++t) {
            const int i = gtid + t * S;
            const bool p = i < n4;
            float4 v0 = p ? dp4[i] : z4;
            float4 v1 = p ? sp4[i] : z4;
            float4 v2 = p ? d4[i]  : z4;
            float4 v3 = p ? s4[i]  : z4;
            process4(a, v0, v1, v2, v3);
        }
    }

    // block reduction via LDS store-then-gather (no shuffles, no atomics)
    #pragma unroll
    for (int k = 0; k < NACC; ++k) red[k][tid] = a[k];     // conflict-free
    __syncthreads();

    if (tid < 192) {
        const int k = tid >> 3;        // 0..23
        const int j = tid & 7;         // 0..7 : owns threads j*32..j*32+31
        const float* row = &red[k][j * 32];
        double s0 = 0.0, s1 = 0.0, s2 = 0.0, s3 = 0.0;
        #pragma unroll
        for (int i = 0; i < 32; i += 4) {
            s0 += (double)row[(i + 0 + tid) & 31];
            s1 += (double)row[(i + 1 + tid) & 31];
            s2 += (double)row[(i + 2 + tid) & 31];
            s3 += (double)row[(i + 3 + tid) & 31];
        }
        red2[k][j] = (s0 + s1) + (s2 + s3);
    }
    __syncthreads();

    if (tid < NACC) {
        double v = 0.0;
        #pragma unroll
        for (int j = 0; j < 8; ++j) v += red2[tid][j];
        // f32 per-block partial; transposed layout: column k contiguous
        partial[tid * GRID1 + blockIdx.x] = (float)v;
    }
}

// 1024 threads = 16 waves; wave w reduces cols {w, w+16}. Each column is
// 1024 f32 = 256 float4; lane l takes float4 indices {l, l+64, l+128, l+192}
// (coalesced, 4 independent loads -> one latency exposure), f64 accumulate,
// then a 6-step f64 shuffle reduce (only 16 waves total, bpermute cost moot).
__global__ __launch_bounds__(1024) void amp_final(
    const float* __restrict__ partial, float* __restrict__ out, int n)
{
    __shared__ double tot[NACC];
    const int lane = threadIdx.x & 63;
    const int wave = threadIdx.x >> 6;

    for (int k = wave; k < NACC; k += 16) {
        const float4* col = (const float4*)(partial + k * GRID1);
        float4 v0 = col[lane];
        float4 v1 = col[lane + 64];
        float4 v2 = col[lane + 128];
        float4 v3 = col[lane + 192];
        double t0 = (double)v0.x + (double)v0.y + (double)v0.z + (double)v0.w;
        double t1 = (double)v1.x + (double)v1.y + (double)v1.z + (double)v1.w;
        double t2 = (double)v2.x + (double)v2.y + (double)v2.z + (double)v2.w;
        double t3 = (double)v3.x + (double)v3.y + (double)v3.z + (double)v3.w;
        double v = (t0 + t1) + (t2 + t3);
        #pragma unroll
        for (int off = 32; off > 0; off >>= 1)
            v += __shfl_down(v, off, 64);
        if (lane == 0) tot[k] = v;
    }
    __syncthreads();

    if (threadIdx.x == 0) {
        const double nf = (double)n;
        const double lt = tot[0];
        const double sum_d  = tot[1], sum_d2  = tot[2];
        const double sum_dp = tot[3], sum_dp2 = tot[4];
        const double sum_s  = tot[5], sum_s2  = tot[6];
        const double sum_sp = tot[7], sum_sp2 = tot[8];

        double scale_cost = 1.0 - lt / nf;

        double d_rst = 0.0, s_rst = 0.0, rst_d = 0.0, rst_s = 0.0;
        int cnt = 0;
        #pragma unroll
        for (int i = 0; i < 5; ++i) {
            double c   = tot[9 + 3 * i];
            double sdi = tot[10 + 3 * i];
            double ssi = tot[11 + 3 * i];
            double safe = fmax(c, 1.0);
            double w = sqrt(log(nf / safe));
            double sum_di = w * sdi;
            double sum_si = w * ssi;
            bool has = c > 0.0;
            double nd = (d_rst + sum_di) / safe;
            double ns = (s_rst + sum_si) / safe;
            if (has) {
                d_rst = nd; s_rst = ns;
                rst_d += nd; rst_s += ns;
                cnt++;
            }
        }
        double denom = (cnt == 0) ? 5.0 : (double)cnt;
        rst_d /= denom;
        rst_s /= denom;

        double mean_d  = sum_d / nf,  mean_dp = sum_dp / nf;
        double mean_s  = sum_s / nf,  mean_sp = sum_sp / nf;
        double var_d  = (sum_d2  - nf * mean_d  * mean_d)  / (nf - 1.0);
        double var_dp = (sum_dp2 - nf * mean_dp * mean_dp) / (nf - 1.0);
        double var_s  = (sum_s2  - nf * mean_s  * mean_s)  / (nf - 1.0);
        double var_sp = (sum_sp2 - nf * mean_sp * mean_sp) / (nf - 1.0);

        double dbp_mean_cost = fabs(mean_d - mean_dp) / mean_d;
        double sbp_mean_cost = fabs(mean_s - mean_sp) / mean_s;
        double dbp_var_cost  = fabs(var_d - var_dp) / var_d;
        double sbp_var_cost  = fabs(var_s - var_sp) / var_s;

        out[0] = (float)(rst_d + dbp_mean_cost + dbp_var_cost);
        out[1] = (float)(rst_s + sbp_mean_cost + sbp_var_cost);
        out[2] = (float)scale_cost;
    }
}

extern "C" void kernel_launch(void* const* d_in, const int* in_sizes, int n_in,
                              void* d_out, int out_size, void* d_ws, size_t ws_size,
                              hipStream_t stream) {
    const float* dp = (const float*)d_in[0];   // dbp_pred
    const float* sp = (const float*)d_in[1];   // sbp_pred
    // d_in[2] = mbp_pred (unused), d_in[5] = m (unused)
    const float* d  = (const float*)d_in[3];
    const float* s  = (const float*)d_in[4];
    const int n = in_sizes[0];

    float* partial = (float*)d_ws;             // NACC * GRID1 f32 = 96 KiB
    float* out = (float*)d_out;

    if (n == GRID1 * TPB * 4 * NTILE) {
        hipLaunchKernelGGL((amp_reduce<true>), dim3(GRID1), dim3(TPB), 0, stream,
                           dp, sp, d, s, partial, n);
    } else {
        hipLaunchKernelGGL((amp_reduce<false>), dim3(GRID1), dim3(TPB), 0, stream,
                           dp, sp, d, s, partial, n);
    }
    hipLaunchKernelGGL(amp_final, dim3(1), dim3(1024), 0, stream,
                       partial, out, n);
}

// Round 14
// 23.675 us; speedup vs baseline: 1.1065x; 1.0552x over previous
//
#include <hip/hip_runtime.h>
#include <math.h>

#define NACC 24
#define GRID1 1024
#define TPB 256
#define NTILE 4
// 1024 blocks x 256 threads x 4 tiles x 4 elems = 4194304 exactly

// canonical 24-vector layout:
//  0: lt count (dbp_pred < sbp_pred)
//  1: sum_d   2: sum_d2   3: sum_dp  4: sum_dp2
//  5: sum_s   6: sum_s2   7: sum_sp  8: sum_sp2
//  9+3g: mask-g count   10+3g: mask-g . smape_d   11+3g: mask-g . smape_s

// Pair-packed accumulation: each accumulator is a float2 ext-vector with
// INDEPENDENT .x/.y chains (elements x,z -> .x ; y,w -> .y), folded once at
// the end. This makes v_pk_fma_f32 / v_pk_add_f32 formation legal without
// reassociation (the scalar version's serial chains could never pack).
// Error class unchanged: f32 partials over 16 elems, ~2e-7 rel; counts <= 16
// exact in f32. Promoted to f64 for the in-block tree; per-block partials f32.
typedef float v2f __attribute__((ext_vector_type(2)));

__device__ __forceinline__ v2f vfma2(v2f a, v2f b, v2f c) {
    return __builtin_elementwise_fma(a, b, c);
}
__device__ __forceinline__ v2f vabs2(v2f a) {
    return __builtin_elementwise_abs(a);
}
__device__ __forceinline__ v2f vrcp2(v2f a) {
    v2f r; r.x = __builtin_amdgcn_rcpf(a.x); r.y = __builtin_amdgcn_rcpf(a.y);
    return r;
}
__device__ __forceinline__ v2f vsel2(bool mx, bool my) {
    v2f r; r.x = mx ? 1.0f : 0.0f; r.y = my ? 1.0f : 0.0f;
    return r;
}

__device__ __forceinline__ void process_pair(v2f* a, v2f dpv, v2f spv,
                                             v2f dv, v2f sv) {
    a[0] += vsel2(dpv.x < spv.x, dpv.y < spv.y);
    a[1] += dv;  a[2] = vfma2(dv,  dv,  a[2]);
    a[3] += dpv; a[4] = vfma2(dpv, dpv, a[4]);
    a[5] += sv;  a[6] = vfma2(sv,  sv,  a[6]);
    a[7] += spv; a[8] = vfma2(spv, spv, a[8]);
    v2f smd = (2.0f * vabs2(dpv - dv)) * vrcp2(vabs2(dpv) + vabs2(dv));
    v2f sms = (2.0f * vabs2(spv - sv)) * vrcp2(vabs2(spv) + vabs2(sv));
    // mask precedence: & binds tighter than | in the reference
    v2f w;
    w = vsel2((sv.x < 120.0f) && (dv.x < 80.0f),
              (sv.y < 120.0f) && (dv.y < 80.0f));
    a[9]  += w; a[10] = vfma2(w, smd, a[10]); a[11] = vfma2(w, sms, a[11]);
    w = vsel2((sv.x >= 120.0f) && (sv.x < 130.0f) && (dv.x < 80.0f),
              (sv.y >= 120.0f) && (sv.y < 130.0f) && (dv.y < 80.0f));
    a[12] += w; a[13] = vfma2(w, smd, a[13]); a[14] = vfma2(w, sms, a[14]);
    w = vsel2(((sv.x >= 130.0f) && (sv.x < 140.0f)) || ((dv.x >= 80.0f) && (dv.x < 90.0f)),
              ((sv.y >= 130.0f) && (sv.y < 140.0f)) || ((dv.y >= 80.0f) && (dv.y < 90.0f)));
    a[15] += w; a[16] = vfma2(w, smd, a[16]); a[17] = vfma2(w, sms, a[17]);
    w = vsel2((sv.x >= 140.0f) || (dv.x >= 90.0f),
              (sv.y >= 140.0f) || (dv.y >= 90.0f));
    a[18] += w; a[19] = vfma2(w, smd, a[19]); a[20] = vfma2(w, sms, a[20]);
    w = vsel2((sv.x > 180.0f) || (dv.x > 120.0f),
              (sv.y > 180.0f) || (dv.y > 120.0f));
    a[21] += w; a[22] = vfma2(w, smd, a[22]); a[23] = vfma2(w, sms, a[23]);
}

__device__ __forceinline__ void process4(v2f* a, float4 vdp, float4 vsp,
                                         float4 vd, float4 vs) {
    v2f dp0 = {vdp.x, vdp.y}, sp0 = {vsp.x, vsp.y};
    v2f d0  = {vd.x,  vd.y},  s0  = {vs.x,  vs.y};
    v2f dp1 = {vdp.z, vdp.w}, sp1 = {vsp.z, vsp.w};
    v2f d1  = {vd.z,  vd.w},  s1  = {vs.z,  vs.w};
    process_pair(a, dp0, sp0, d0, s0);
    process_pair(a, dp1, sp1, d1, s1);
}

// Round-11 grind (distance-1 double-buffered register pipeline) with packed
// accumulators; per-block partial store is f32 (round 13).
template <bool EXACT>
__global__ __launch_bounds__(TPB, 4) void amp_reduce(
    const float* __restrict__ dp, const float* __restrict__ sp,
    const float* __restrict__ d,  const float* __restrict__ s,
    float* __restrict__ partial, int n)
{
    __shared__ float  red[NACC][TPB];   // 24 KB
    __shared__ double red2[NACC][8];    // 1.5 KB

    const int tid  = threadIdx.x;
    const int n4   = n >> 2;
    const int gtid = blockIdx.x * TPB + tid;
    const int S    = GRID1 * TPB;       // float4 stride between tiles

    const float4* dp4 = (const float4*)dp;
    const float4* sp4 = (const float4*)sp;
    const float4* d4  = (const float4*)d;
    const float4* s4  = (const float4*)s;

    v2f a[NACC];
    #pragma unroll
    for (int k = 0; k < NACC; ++k) a[k] = (v2f){0.0f, 0.0f};

    if (EXACT) {
        int i = gtid;
        // prologue: tiles 0 and 1 in flight
        float4 A0 = dp4[i], A1 = sp4[i], A2 = d4[i], A3 = s4[i];
        i += S;
        float4 B0 = dp4[i], B1 = sp4[i], B2 = d4[i], B3 = s4[i];
        __builtin_amdgcn_sched_barrier(0);
        process4(a, A0, A1, A2, A3);            // tile 0 (covers tile 1)
        i += S;
        A0 = dp4[i]; A1 = sp4[i]; A2 = d4[i]; A3 = s4[i];   // tile 2
        __builtin_amdgcn_sched_barrier(0);
        process4(a, B0, B1, B2, B3);            // tile 1 (covers tile 2)
        i += S;
        B0 = dp4[i]; B1 = sp4[i]; B2 = d4[i]; B3 = s4[i];   // tile 3
        __builtin_amdgcn_sched_barrier(0);
        process4(a, A0, A1, A2, A3);            // tile 2 (covers tile 3)
        process4(a, B0, B1, B2, B3);            // tile 3
    } else {
        const float4 z4 = make_float4(0.f, 0.f, 0.f, 0.f);
        #pragma unroll
        for (int t = 0; t < NTILE; ++t) {
            const int i = gtid + t * S;
            const bool p = i < n4;
            float4 v0 = p ? dp4[i] : z4;
            float4 v1 = p ? sp4[i] : z4;
            float4 v2 = p ? d4[i]  : z4;
            float4 v3 = p ? s4[i]  : z4;
            process4(a, v0, v1, v2, v3);
        }
    }

    // fold pair lanes, then block reduction via LDS store-then-gather
    #pragma unroll
    for (int k = 0; k < NACC; ++k) red[k][tid] = a[k].x + a[k].y;
    __syncthreads();

    if (tid < 192) {
        const int k = tid >> 3;        // 0..23
        const int j = tid & 7;         // 0..7 : owns threads j*32..j*32+31
        const float* row = &red[k][j * 32];
        double s0 = 0.0, s1 = 0.0, s2 = 0.0, s3 = 0.0;
        #pragma unroll
        for (int i = 0; i < 32; i += 4) {
            s0 += (double)row[(i + 0 + tid) & 31];
            s1 += (double)row[(i + 1 + tid) & 31];
            s2 += (double)row[(i + 2 + tid) & 31];
            s3 += (double)row[(i + 3 + tid) & 31];
        }
        red2[k][j] = (s0 + s1) + (s2 + s3);
    }
    __syncthreads();

    if (tid < NACC) {
        double v = 0.0;
        #pragma unroll
        for (int j = 0; j < 8; ++j) v += red2[tid][j];
        // f32 per-block partial; transposed layout: column k contiguous
        partial[tid * GRID1 + blockIdx.x] = (float)v;
    }
}

// 1024 threads = 16 waves; wave w reduces cols {w, w+16}. Each column is
// 1024 f32 = 256 float4; lane l takes float4 indices {l, l+64, l+128, l+192}
// (coalesced, 4 independent loads), f64 accumulate, 6-step shuffle reduce.
__global__ __launch_bounds__(1024) void amp_final(
    const float* __restrict__ partial, float* __restrict__ out, int n)
{
    __shared__ double tot[NACC];
    const int lane = threadIdx.x & 63;
    const int wave = threadIdx.x >> 6;

    for (int k = wave; k < NACC; k += 16) {
        const float4* col = (const float4*)(partial + k * GRID1);
        float4 v0 = col[lane];
        float4 v1 = col[lane + 64];
        float4 v2 = col[lane + 128];
        float4 v3 = col[lane + 192];
        double t0 = (double)v0.x + (double)v0.y + (double)v0.z + (double)v0.w;
        double t1 = (double)v1.x + (double)v1.y + (double)v1.z + (double)v1.w;
        double t2 = (double)v2.x + (double)v2.y + (double)v2.z + (double)v2.w;
        double t3 = (double)v3.x + (double)v3.y + (double)v3.z + (double)v3.w;
        double v = (t0 + t1) + (t2 + t3);
        #pragma unroll
        for (int off = 32; off > 0; off >>= 1)
            v += __shfl_down(v, off, 64);
        if (lane == 0) tot[k] = v;
    }
    __syncthreads();

    if (threadIdx.x == 0) {
        const double nf = (double)n;
        const double lt = tot[0];
        const double sum_d  = tot[1], sum_d2  = tot[2];
        const double sum_dp = tot[3], sum_dp2 = tot[4];
        const double sum_s  = tot[5], sum_s2  = tot[6];
        const double sum_sp = tot[7], sum_sp2 = tot[8];

        double scale_cost = 1.0 - lt / nf;

        double d_rst = 0.0, s_rst = 0.0, rst_d = 0.0, rst_s = 0.0;
        int cnt = 0;
        #pragma unroll
        for (int i = 0; i < 5; ++i) {
            double c   = tot[9 + 3 * i];
            double sdi = tot[10 + 3 * i];
            double ssi = tot[11 + 3 * i];
            double safe = fmax(c, 1.0);
            double w = sqrt(log(nf / safe));
            double sum_di = w * sdi;
            double sum_si = w * ssi;
            bool has = c > 0.0;
            double nd = (d_rst + sum_di) / safe;
            double ns = (s_rst + sum_si) / safe;
            if (has) {
                d_rst = nd; s_rst = ns;
                rst_d += nd; rst_s += ns;
                cnt++;
            }
        }
        double denom = (cnt == 0) ? 5.0 : (double)cnt;
        rst_d /= denom;
        rst_s /= denom;

        double mean_d  = sum_d / nf,  mean_dp = sum_dp / nf;
        double mean_s  = sum_s / nf,  mean_sp = sum_sp / nf;
        double var_d  = (sum_d2  - nf * mean_d  * mean_d)  / (nf - 1.0);
        double var_dp = (sum_dp2 - nf * mean_dp * mean_dp) / (nf - 1.0);
        double var_s  = (sum_s2  - nf * mean_s  * mean_s)  / (nf - 1.0);
        double var_sp = (sum_sp2 - nf * mean_sp * mean_sp) / (nf - 1.0);

        double dbp_mean_cost = fabs(mean_d - mean_dp) / mean_d;
        double sbp_mean_cost = fabs(mean_s - mean_sp) / mean_s;
        double dbp_var_cost  = fabs(var_d - var_dp) / var_d;
        double sbp_var_cost  = fabs(var_s - var_sp) / var_s;

        out[0] = (float)(rst_d + dbp_mean_cost + dbp_var_cost);
        out[1] = (float)(rst_s + sbp_mean_cost + sbp_var_cost);
        out[2] = (float)scale_cost;
    }
}

extern "C" void kernel_launch(void* const* d_in, const int* in_sizes, int n_in,
                              void* d_out, int out_size, void* d_ws, size_t ws_size,
                              hipStream_t stream) {
    const float* dp = (const float*)d_in[0];   // dbp_pred
    const float* sp = (const float*)d_in[1];   // sbp_pred
    // d_in[2] = mbp_pred (unused), d_in[5] = m (unused)
    const float* d  = (const float*)d_in[3];
    const float* s  = (const float*)d_in[4];
    const int n = in_sizes[0];

    float* partial = (float*)d_ws;             // NACC * GRID1 f32 = 96 KiB
    float* out = (float*)d_out;

    if (n == GRID1 * TPB * 4 * NTILE) {
        hipLaunchKernelGGL((amp_reduce<true>), dim3(GRID1), dim3(TPB), 0, stream,
                           dp, sp, d, s, partial, n);
    } else {
        hipLaunchKernelGGL((amp_reduce<false>), dim3(GRID1), dim3(TPB), 0, stream,
                           dp, sp, d, s, partial, n);
    }
    hipLaunchKernelGGL(amp_final, dim3(1), dim3(1024), 0, stream,
                       partial, out, n);
}

// Round 16
// 20.807 us; speedup vs baseline: 1.2590x; 1.1379x over previous
//
#include <hip/hip_runtime.h>
#include <math.h>

#define NACC 24
#define GRID1 1024
#define TPB 256
#define NTILE 4
// 1024 blocks x 256 threads x 4 tiles x 4 elems = 4194304 exactly

// canonical 24-vector layout:
//  0: lt count (dbp_pred < sbp_pred)
//  1: sum_d   2: sum_d2   3: sum_dp  4: sum_dp2
//  5: sum_s   6: sum_s2   7: sum_sp  8: sum_sp2
//  9+3g: mask-g count   10+3g: mask-g . smape_d   11+3g: mask-g . smape_s

// Pair-packed accumulation (round 14): float2 ext-vector accumulators with
// independent .x/.y chains -> v_pk_fma/add formation legal without
// reassociation. f32 partials over 16 elems (~2e-7 rel), counts exact,
// f64 in-block tree, f32 per-block partials.
typedef float v2f __attribute__((ext_vector_type(2)));
typedef float v4f __attribute__((ext_vector_type(4)));   // NT-load-compatible

__device__ __forceinline__ v2f vfma2(v2f a, v2f b, v2f c) {
    return __builtin_elementwise_fma(a, b, c);
}
__device__ __forceinline__ v2f vabs2(v2f a) {
    return __builtin_elementwise_abs(a);
}
__device__ __forceinline__ v2f vrcp2(v2f a) {
    v2f r; r.x = __builtin_amdgcn_rcpf(a.x); r.y = __builtin_amdgcn_rcpf(a.y);
    return r;
}
__device__ __forceinline__ v2f vsel2(bool mx, bool my) {
    v2f r; r.x = mx ? 1.0f : 0.0f; r.y = my ? 1.0f : 0.0f;
    return r;
}

__device__ __forceinline__ void process_pair(v2f* a, v2f dpv, v2f spv,
                                             v2f dv, v2f sv) {
    a[0] += vsel2(dpv.x < spv.x, dpv.y < spv.y);
    a[1] += dv;  a[2] = vfma2(dv,  dv,  a[2]);
    a[3] += dpv; a[4] = vfma2(dpv, dpv, a[4]);
    a[5] += sv;  a[6] = vfma2(sv,  sv,  a[6]);
    a[7] += spv; a[8] = vfma2(spv, spv, a[8]);
    v2f smd = (2.0f * vabs2(dpv - dv)) * vrcp2(vabs2(dpv) + vabs2(dv));
    v2f sms = (2.0f * vabs2(spv - sv)) * vrcp2(vabs2(spv) + vabs2(sv));
    // mask precedence: & binds tighter than | in the reference
    v2f w;
    w = vsel2((sv.x < 120.0f) && (dv.x < 80.0f),
              (sv.y < 120.0f) && (dv.y < 80.0f));
    a[9]  += w; a[10] = vfma2(w, smd, a[10]); a[11] = vfma2(w, sms, a[11]);
    w = vsel2((sv.x >= 120.0f) && (sv.x < 130.0f) && (dv.x < 80.0f),
              (sv.y >= 120.0f) && (sv.y < 130.0f) && (dv.y < 80.0f));
    a[12] += w; a[13] = vfma2(w, smd, a[13]); a[14] = vfma2(w, sms, a[14]);
    w = vsel2(((sv.x >= 130.0f) && (sv.x < 140.0f)) || ((dv.x >= 80.0f) && (dv.x < 90.0f)),
              ((sv.y >= 130.0f) && (sv.y < 140.0f)) || ((dv.y >= 80.0f) && (dv.y < 90.0f)));
    a[15] += w; a[16] = vfma2(w, smd, a[16]); a[17] = vfma2(w, sms, a[17]);
    w = vsel2((sv.x >= 140.0f) || (dv.x >= 90.0f),
              (sv.y >= 140.0f) || (dv.y >= 90.0f));
    a[18] += w; a[19] = vfma2(w, smd, a[19]); a[20] = vfma2(w, sms, a[20]);
    w = vsel2((sv.x > 180.0f) || (dv.x > 120.0f),
              (sv.y > 180.0f) || (dv.y > 120.0f));
    a[21] += w; a[22] = vfma2(w, smd, a[22]); a[23] = vfma2(w, sms, a[23]);
}

__device__ __forceinline__ void process4(v2f* a, v4f vdp, v4f vsp,
                                         v4f vd, v4f vs) {
    v2f dp0 = {vdp.x, vdp.y}, sp0 = {vsp.x, vsp.y};
    v2f d0  = {vd.x,  vd.y},  s0  = {vs.x,  vs.y};
    v2f dp1 = {vdp.z, vdp.w}, sp1 = {vsp.z, vsp.w};
    v2f d1  = {vd.z,  vd.w},  s1  = {vs.z,  vs.w};
    process_pair(a, dp0, sp0, d0, s0);
    process_pair(a, dp1, sp1, d1, s1);
}

// NT loads: 64 MiB streamed once per call has ZERO L2 reuse (each XCD pushes
// ~8 MiB through its 4 MiB L2 at 100% miss+evict). `nt` bypasses L2
// allocation so the stream comes from L3/HBM without the evict churn.
// (Must go through a clang ext-vector pointer: __builtin_nontemporal_load
// rejects HIP_vector_type<float,4>*.)
__device__ __forceinline__ v4f ldnt(const float* p) {
    return __builtin_nontemporal_load((const v4f*)p);
}

// Round-11 grind (distance-1 double-buffered register pipeline, packed
// accumulators) with nontemporal loads; f32 per-block partial store.
template <bool EXACT>
__global__ __launch_bounds__(TPB, 4) void amp_reduce(
    const float* __restrict__ dp, const float* __restrict__ sp,
    const float* __restrict__ d,  const float* __restrict__ s,
    float* __restrict__ partial, int n)
{
    __shared__ float  red[NACC][TPB];   // 24 KB
    __shared__ double red2[NACC][8];    // 1.5 KB

    const int tid  = threadIdx.x;
    const int n4   = n >> 2;
    const int gtid = blockIdx.x * TPB + tid;
    const int S    = GRID1 * TPB;       // float4 stride between tiles

    v2f a[NACC];
    #pragma unroll
    for (int k = 0; k < NACC; ++k) a[k] = (v2f){0.0f, 0.0f};

    if (EXACT) {
        int i = gtid;
        // prologue: tiles 0 and 1 in flight
        v4f A0 = ldnt(dp + 4 * i), A1 = ldnt(sp + 4 * i),
            A2 = ldnt(d + 4 * i),  A3 = ldnt(s + 4 * i);
        i += S;
        v4f B0 = ldnt(dp + 4 * i), B1 = ldnt(sp + 4 * i),
            B2 = ldnt(d + 4 * i),  B3 = ldnt(s + 4 * i);
        __builtin_amdgcn_sched_barrier(0);
        process4(a, A0, A1, A2, A3);            // tile 0 (covers tile 1)
        i += S;
        A0 = ldnt(dp + 4 * i); A1 = ldnt(sp + 4 * i);
        A2 = ldnt(d + 4 * i);  A3 = ldnt(s + 4 * i);        // tile 2
        __builtin_amdgcn_sched_barrier(0);
        process4(a, B0, B1, B2, B3);            // tile 1 (covers tile 2)
        i += S;
        B0 = ldnt(dp + 4 * i); B1 = ldnt(sp + 4 * i);
        B2 = ldnt(d + 4 * i);  B3 = ldnt(s + 4 * i);        // tile 3
        __builtin_amdgcn_sched_barrier(0);
        process4(a, A0, A1, A2, A3);            // tile 2 (covers tile 3)
        process4(a, B0, B1, B2, B3);            // tile 3
    } else {
        const v4f z4 = {0.f, 0.f, 0.f, 0.f};
        #pragma unroll
        for (int t = 0; t < NTILE; ++t) {
            const int i = gtid + t * S;
            const bool p = i < n4;
            v4f v0 = p ? *(const v4f*)(dp + 4 * i) : z4;
            v4f v1 = p ? *(const v4f*)(sp + 4 * i) : z4;
            v4f v2 = p ? *(const v4f*)(d + 4 * i)  : z4;
            v4f v3 = p ? *(const v4f*)(s + 4 * i)  : z4;
            process4(a, v0, v1, v2, v3);
        }
    }

    // fold pair lanes, then block reduction via LDS store-then-gather
    #pragma unroll
    for (int k = 0; k < NACC; ++k) red[k][tid] = a[k].x + a[k].y;
    __syncthreads();

    if (tid < 192) {
        const int k = tid >> 3;        // 0..23
        const int j = tid & 7;         // 0..7 : owns threads j*32..j*32+31
        const float* row = &red[k][j * 32];
        double s0 = 0.0, s1 = 0.0, s2 = 0.0, s3 = 0.0;
        #pragma unroll
        for (int i = 0; i < 32; i += 4) {
            s0 += (double)row[(i + 0 + tid) & 31];
            s1 += (double)row[(i + 1 + tid) & 31];
            s2 += (double)row[(i + 2 + tid) & 31];
            s3 += (double)row[(i + 3 + tid) & 31];
        }
        red2[k][j] = (s0 + s1) + (s2 + s3);
    }
    __syncthreads();

    if (tid < NACC) {
        double v = 0.0;
        #pragma unroll
        for (int j = 0; j < 8; ++j) v += red2[tid][j];
        // f32 per-block partial; transposed layout: column k contiguous
        partial[tid * GRID1 + blockIdx.x] = (float)v;
    }
}

// 1024 threads = 16 waves; wave w reduces cols {w, w+16}; float4 column
// reads, f64 accumulate, 6-step shuffle reduce, scalar tail on thread 0.
__global__ __launch_bounds__(1024) void amp_final(
    const float* __restrict__ partial, float* __restrict__ out, int n)
{
    __shared__ double tot[NACC];
    const int lane = threadIdx.x & 63;
    const int wave = threadIdx.x >> 6;

    for (int k = wave; k < NACC; k += 16) {
        const float4* col = (const float4*)(partial + k * GRID1);
        float4 v0 = col[lane];
        float4 v1 = col[lane + 64];
        float4 v2 = col[lane + 128];
        float4 v3 = col[lane + 192];
        double t0 = (double)v0.x + (double)v0.y + (double)v0.z + (double)v0.w;
        double t1 = (double)v1.x + (double)v1.y + (double)v1.z + (double)v1.w;
        double t2 = (double)v2.x + (double)v2.y + (double)v2.z + (double)v2.w;
        double t3 = (double)v3.x + (double)v3.y + (double)v3.z + (double)v3.w;
        double v = (t0 + t1) + (t2 + t3);
        #pragma unroll
        for (int off = 32; off > 0; off >>= 1)
            v += __shfl_down(v, off, 64);
        if (lane == 0) tot[k] = v;
    }
    __syncthreads();

    if (threadIdx.x == 0) {
        const double nf = (double)n;
        const double lt = tot[0];
        const double sum_d  = tot[1], sum_d2  = tot[2];
        const double sum_dp = tot[3], sum_dp2 = tot[4];
        const double sum_s  = tot[5], sum_s2  = tot[6];
        const double sum_sp = tot[7], sum_sp2 = tot[8];

        double scale_cost = 1.0 - lt / nf;

        double d_rst = 0.0, s_rst = 0.0, rst_d = 0.0, rst_s = 0.0;
        int cnt = 0;
        #pragma unroll
        for (int i = 0; i < 5; ++i) {
            double c   = tot[9 + 3 * i];
            double sdi = tot[10 + 3 * i];
            double ssi = tot[11 + 3 * i];
            double safe = fmax(c, 1.0);
            double w = sqrt(log(nf / safe));
            double sum_di = w * sdi;
            double sum_si = w * ssi;
            bool has = c > 0.0;
            double nd = (d_rst + sum_di) / safe;
            double ns = (s_rst + sum_si) / safe;
            if (has) {
                d_rst = nd; s_rst = ns;
                rst_d += nd; rst_s += ns;
                cnt++;
            }
        }
        double denom = (cnt == 0) ? 5.0 : (double)cnt;
        rst_d /= denom;
        rst_s /= denom;

        double mean_d  = sum_d / nf,  mean_dp = sum_dp / nf;
        double mean_s  = sum_s / nf,  mean_sp = sum_sp / nf;
        double var_d  = (sum_d2  - nf * mean_d  * mean_d)  / (nf - 1.0);
        double var_dp = (sum_dp2 - nf * mean_dp * mean_dp) / (nf - 1.0);
        double var_s  = (sum_s2  - nf * mean_s  * mean_s)  / (nf - 1.0);
        double var_sp = (sum_sp2 - nf * mean_sp * mean_sp) / (nf - 1.0);

        double dbp_mean_cost = fabs(mean_d - mean_dp) / mean_d;
        double sbp_mean_cost = fabs(mean_s - mean_sp) / mean_s;
        double dbp_var_cost  = fabs(var_d - var_dp) / var_d;
        double sbp_var_cost  = fabs(var_s - var_sp) / var_s;

        out[0] = (float)(rst_d + dbp_mean_cost + dbp_var_cost);
        out[1] = (float)(rst_s + sbp_mean_cost + sbp_var_cost);
        out[2] = (float)scale_cost;
    }
}

extern "C" void kernel_launch(void* const* d_in, const int* in_sizes, int n_in,
                              void* d_out, int out_size, void* d_ws, size_t ws_size,
                              hipStream_t stream) {
    const float* dp = (const float*)d_in[0];   // dbp_pred
    const float* sp = (const float*)d_in[1];   // sbp_pred
    // d_in[2] = mbp_pred (unused), d_in[5] = m (unused)
    const float* d  = (const float*)d_in[3];
    const float* s  = (const float*)d_in[4];
    const int n = in_sizes[0];

    float* partial = (float*)d_ws;             // NACC * GRID1 f32 = 96 KiB
    float* out = (float*)d_out;

    if (n == GRID1 * TPB * 4 * NTILE) {
        hipLaunchKernelGGL((amp_reduce<true>), dim3(GRID1), dim3(TPB), 0, stream,
                           dp, sp, d, s, partial, n);
    } else {
        hipLaunchKernelGGL((amp_reduce<false>), dim3(GRID1), dim3(TPB), 0, stream,
                           dp, sp, d, s, partial, n);
    }
    hipLaunchKernelGGL(amp_final, dim3(1), dim3(1024), 0, stream,
                       partial, out, n);
}